// Round 4
// baseline (257.639 us; speedup 1.0000x reference)
//
#include <hip/hip_runtime.h>

#define K  100   // NUM_BREAKPOINTS
#define NB 1024  // LUT buckets (power of 2 -> exact fp bucket math)

typedef float fvec4 __attribute__((ext_vector_type(4)));

// ---------------------------------------------------------------------------
// Two-level branch-free LUT.
// Level 1 (per bucket): split0, split1 (+inf if unused). split0's low
// mantissa byte is REPLACED by: bits[6:0] = base count lo (= #breakpoints <=
// bucket left edge, <=100), bit[7] = overflow marker (>=3 interior bps).
// The <=2^-15 relative perturbation of split0 shifts one breakpoint by
// <=3e-5; PWL continuity bounds the output error at ~1e-5 (tol 3.9e-3).
// Level 2: segment (a,b) arrays indexed by idx = max(lo + (x>=s0) + (x>=s1)
// - 1, 0)  -- pure VALU, no branch, no search on the hot path.
//
// ws layout (9392 B, within proven 9504):
//  [0,4096)    float s0_g[NB]
//  [4096,8192) float s1_g[NB]
//  [8192,8592) float sa_g[K]
//  [8592,8992) float sb_g[K]
//  [8992,9392) float sx_g[K]   (sorted bps, for the ~never overflow fallback)
// ---------------------------------------------------------------------------
__global__ __launch_bounds__(1024) void pwl_setup_kernel(
    const float* __restrict__ xp, const float* __restrict__ sl,
    const float* __restrict__ bias, float* __restrict__ s0_g,
    float* __restrict__ s1_g, float* __restrict__ sa_g,
    float* __restrict__ sb_g, float* __restrict__ sx_g) {
  __shared__ float s_pos[K];
  __shared__ float s_slope[K];
  __shared__ float s_x[K];    // sorted breakpoints
  __shared__ float s_c[K];    // scan scratch
  __shared__ float s_sa[K];   // per-segment slope
  __shared__ float s_sb[K];   // per-segment intercept
  __shared__ unsigned short s_cnt[NB + 1];
  const int t = threadIdx.x;

  if (t < K) { s_pos[t] = xp[t]; s_slope[t] = sl[t]; }
  __syncthreads();

  // O(K^2) stable rank sort (ties broken by original index)
  if (t < K) {
    float v = s_pos[t];
    int r = 0;
    for (int j = 0; j < K; ++j) {
      float u = s_pos[j];
      r += ((u < v) || (u == v && j < t)) ? 1 : 0;
    }
    s_x[r] = v;
  }
  __syncthreads();

  // contributions c[i] = (sx[i+1]-sx[i]) * slope[i]
  if (t < K - 1) s_c[t] = (s_x[t + 1] - s_x[t]) * s_slope[t];
  __syncthreads();
  // Hillis-Steele inclusive scan (7 rounds)
  for (int off = 1; off < K - 1; off <<= 1) {
    float v = 0.0f;
    if (t >= off && t < K - 1) v = s_c[t - off];
    __syncthreads();
    if (t < K - 1) s_c[t] += v;
    __syncthreads();
  }
  // beta[i] = bias + cum[i-1]; fold to y = a*x + (beta - sx*a)
  if (t < K) {
    float beta = bias[0] + (t ? s_c[t - 1] : 0.0f);
    float a = s_slope[t];
    s_sa[t] = a;
    s_sb[t] = beta - s_x[t] * a;
  }
  __syncthreads();

  if (t < K) {
    sa_g[t] = s_sa[t];
    sb_g[t] = s_sb[t];
    sx_g[t] = s_x[t];
  }

  // cnt[e] = #breakpoints <= e/NB, via binary upper_bound
  for (int e = t; e <= NB; e += blockDim.x) {
    float ev = (float)e * (1.0f / (float)NB);  // exact (pow2 scale)
    int lo = 0, hi = K;
    while (lo < hi) {
      int mid = (lo + hi) >> 1;
      if (s_x[mid] <= ev) lo = mid + 1; else hi = mid;
    }
    s_cnt[e] = (unsigned short)lo;
  }
  __syncthreads();

  // level-1 bucket table
  for (int b = t; b < NB; b += blockDim.x) {
    int lo = s_cnt[b], hi = s_cnt[b + 1];
    int m = hi - lo;
    float s0 = (m >= 1) ? s_x[lo] : __builtin_huge_valf();
    float s1 = (m >= 2) ? s_x[lo + 1] : __builtin_huge_valf();
    unsigned enc = (unsigned)lo | ((m > 2) ? 0x80u : 0u);  // lo<=100 fits 7 bits
    unsigned u = (__float_as_uint(s0) & 0xFFFFFF00u) | enc;
    s0_g[b] = __uint_as_float(u);  // inf+low-bits -> NaN: compares false, ok
    s1_g[b] = s1;
  }
}

// ---------------------------------------------------------------------------
// Main streaming kernel: branch-free two-level gather, all LDS reads for 4
// elements batched (single waitcnt per level), depth-2 global pipeline.
// Plain loads (x is L3-resident from the harness restore copy; FETCH=67MB of
// 134MB confirmed round 3), nontemporal stores.
// ---------------------------------------------------------------------------
__device__ __forceinline__ int pwl_gsearch(const float* __restrict__ sx,
                                           float xv) {
  int lo = 0, hi = K;
  while (lo < hi) {
    int mid = (lo + hi) >> 1;
    if (sx[mid] <= xv) lo = mid + 1; else hi = mid;
  }
  return max(lo - 1, 0);
}

__device__ __forceinline__ fvec4 pwl_eval4(fvec4 v,
    const float* __restrict__ s_s0, const float* __restrict__ s_s1,
    const float* __restrict__ s_sa, const float* __restrict__ s_sb,
    const float* __restrict__ sx_g) {
  int b0 = min(max((int)(v.x * (float)NB), 0), NB - 1);
  int b1 = min(max((int)(v.y * (float)NB), 0), NB - 1);
  int b2 = min(max((int)(v.z * (float)NB), 0), NB - 1);
  int b3 = min(max((int)(v.w * (float)NB), 0), NB - 1);
  // level-1: 8 independent LDS reads, one wait
  unsigned u0 = __float_as_uint(s_s0[b0]);
  unsigned u1 = __float_as_uint(s_s0[b1]);
  unsigned u2 = __float_as_uint(s_s0[b2]);
  unsigned u3 = __float_as_uint(s_s0[b3]);
  float t0 = s_s1[b0], t1 = s_s1[b1], t2 = s_s1[b2], t3 = s_s1[b3];
  int i0 = max((int)(u0 & 0x7fu) + (int)(v.x >= __uint_as_float(u0)) + (int)(v.x >= t0) - 1, 0);
  int i1 = max((int)(u1 & 0x7fu) + (int)(v.y >= __uint_as_float(u1)) + (int)(v.y >= t1) - 1, 0);
  int i2 = max((int)(u2 & 0x7fu) + (int)(v.z >= __uint_as_float(u2)) + (int)(v.z >= t2) - 1, 0);
  int i3 = max((int)(u3 & 0x7fu) + (int)(v.w >= __uint_as_float(u3)) + (int)(v.w >= t3) - 1, 0);
  // >=3 bps in one bucket: statistically ~never (expected 0.15 buckets/input)
  if (__builtin_expect(((u0 | u1 | u2 | u3) & 0x80u) != 0, 0)) {
    if (u0 & 0x80u) i0 = pwl_gsearch(sx_g, v.x);
    if (u1 & 0x80u) i1 = pwl_gsearch(sx_g, v.y);
    if (u2 & 0x80u) i2 = pwl_gsearch(sx_g, v.z);
    if (u3 & 0x80u) i3 = pwl_gsearch(sx_g, v.w);
  }
  // level-2: 8 independent LDS reads, one wait
  float a0 = s_sa[i0], a1 = s_sa[i1], a2 = s_sa[i2], a3 = s_sa[i3];
  float c0 = s_sb[i0], c1 = s_sb[i1], c2 = s_sb[i2], c3 = s_sb[i3];
  fvec4 r;
  r.x = fminf(fmaxf(fmaf(v.x, a0, c0), 0.0f), 1.0f);
  r.y = fminf(fmaxf(fmaf(v.y, a1, c1), 0.0f), 1.0f);
  r.z = fminf(fmaxf(fmaf(v.z, a2, c2), 0.0f), 1.0f);
  r.w = fminf(fmaxf(fmaf(v.w, a3, c3), 0.0f), 1.0f);
  return r;
}

__device__ __forceinline__ float pwl_eval1(float xv,
    const float* __restrict__ s_s0, const float* __restrict__ s_s1,
    const float* __restrict__ s_sa, const float* __restrict__ s_sb,
    const float* __restrict__ sx_g) {
  int b = min(max((int)(xv * (float)NB), 0), NB - 1);
  unsigned u = __float_as_uint(s_s0[b]);
  float t = s_s1[b];
  int idx = max((int)(u & 0x7fu) + (int)(xv >= __uint_as_float(u)) + (int)(xv >= t) - 1, 0);
  if (__builtin_expect((u & 0x80u) != 0, 0)) idx = pwl_gsearch(sx_g, xv);
  return fminf(fmaxf(fmaf(xv, s_sa[idx], s_sb[idx]), 0.0f), 1.0f);
}

__global__ __launch_bounds__(256) void pwl_main_kernel(
    const fvec4* __restrict__ x, const float* __restrict__ s0_g,
    const float* __restrict__ s1_g, const float* __restrict__ sa_g,
    const float* __restrict__ sb_g, const float* __restrict__ sx_g,
    fvec4* __restrict__ out, int n4, int n) {
  __shared__ float s_s0[NB];
  __shared__ float s_s1[NB];
  __shared__ float s_sa[K];
  __shared__ float s_sb[K];
  for (int i = threadIdx.x; i < NB; i += blockDim.x) {
    s_s0[i] = s0_g[i];
    s_s1[i] = s1_g[i];
  }
  if (threadIdx.x < K) {
    s_sa[threadIdx.x] = sa_g[threadIdx.x];
    s_sb[threadIdx.x] = sb_g[threadIdx.x];
  }
  __syncthreads();

  const int stride = gridDim.x * blockDim.x;
  int i = blockIdx.x * blockDim.x + threadIdx.x;
  if (i < n4) {
    fvec4 v0 = x[i];
    int i1 = i + stride;
    bool h1 = i1 < n4;
    fvec4 v1 = {};
    if (h1) v1 = x[i1];
    while (true) {
      int j0 = i + 2 * stride;
      int j1 = i + 3 * stride;
      bool g0 = j0 < n4;
      bool g1 = j1 < n4;
      fvec4 w0 = {}, w1 = {};
      if (g0) w0 = x[j0];
      if (g1) w1 = x[j1];

      fvec4 r0 = pwl_eval4(v0, s_s0, s_s1, s_sa, s_sb, sx_g);
      __builtin_nontemporal_store(r0, &out[i]);
      if (h1) {
        fvec4 r1 = pwl_eval4(v1, s_s0, s_s1, s_sa, s_sb, sx_g);
        __builtin_nontemporal_store(r1, &out[i1]);
      }

      if (!g0) break;
      i = j0; i1 = j1;
      v0 = w0; v1 = w1;
      h1 = g1;
    }
  }

  // scalar tail (n % 4), handled by block 0 (empty for this shape)
  if (blockIdx.x == 0) {
    const float* xs = (const float*)x;
    float* os = (float*)out;
    for (int j = (n4 << 2) + threadIdx.x; j < n; j += blockDim.x) {
      os[j] = pwl_eval1(xs[j], s_s0, s_s1, s_sa, s_sb, sx_g);
    }
  }
}

extern "C" void kernel_launch(void* const* d_in, const int* in_sizes, int n_in,
                              void* d_out, int out_size, void* d_ws, size_t ws_size,
                              hipStream_t stream) {
  const float* x    = (const float*)d_in[0];
  const float* xp   = (const float*)d_in[1];
  const float* sl   = (const float*)d_in[2];
  const float* bias = (const float*)d_in[3];
  float* out = (float*)d_out;

  float* s0 = (float*)d_ws;                           // 4096 B
  float* s1 = (float*)((char*)d_ws + 4096);           // 4096 B
  float* sa = (float*)((char*)d_ws + 8192);           // 400 B
  float* sb = (float*)((char*)d_ws + 8592);           // 400 B
  float* sx = (float*)((char*)d_ws + 8992);           // 400 B

  const int n  = in_sizes[0];
  const int n4 = n >> 2;

  pwl_setup_kernel<<<1, 1024, 0, stream>>>(xp, sl, bias, s0, s1, sa, sb, sx);

  const int threads = 256;
  const int blocks  = 2048;  // 8 blocks/CU * 4 waves = full 32 waves/CU
  pwl_main_kernel<<<blocks, threads, 0, stream>>>(
      (const fvec4*)x, s0, s1, sa, sb, sx, (fvec4*)out, n4, n);
}

// Round 5
// 251.221 us; speedup vs baseline: 1.0255x; 1.0255x over previous
//
#include <hip/hip_runtime.h>

#define K  100   // NUM_BREAKPOINTS
#define NB 1024  // LUT buckets (power of 2 -> exact fp bucket math)

typedef float fvec4 __attribute__((ext_vector_type(4)));

// ---------------------------------------------------------------------------
// Back to the measured-best gather structure (rd0): ONE ds_read_b64 per
// element from an AoS float2 direct table; dirty buckets hold
// (+inf, packed lo|hi<<16) and take a rare short search.
// Rd4 proved gather count dominates: 16 b32/fvec4 cost +13us vs 8 b32.
// This round: 4 b64/fvec4, batched 8-wide across TWO fvec4 per iteration so
// the ~120cyc LDS latency is paid once per 8 elements, dirty branch once per
// 8 elements, depth-2 global prefetch. launch_bounds(256,8) keeps VGPR<=64
// so full 32 waves/CU survive the wider unroll.
//
// ws layout: [0,8192)      float2 bab[NB]
//            [8192,8592)   f32 sx[K]
//            [8704,9504)   float2 ab[K]
// ---------------------------------------------------------------------------
__global__ __launch_bounds__(1024) void pwl_setup_kernel(
    const float* __restrict__ xp, const float* __restrict__ sl,
    const float* __restrict__ bias, float2* __restrict__ bab_g,
    float* __restrict__ sx_g, float2* __restrict__ ab_g) {
  __shared__ float s_pos[K];
  __shared__ float s_slope[K];
  __shared__ float s_x[K];    // sorted breakpoints
  __shared__ float s_c[K];    // scan scratch
  __shared__ float s_sa[K];   // per-segment slope
  __shared__ float s_sb[K];   // per-segment intercept
  __shared__ unsigned short s_cnt[NB + 1];
  const int t = threadIdx.x;

  if (t < K) { s_pos[t] = xp[t]; s_slope[t] = sl[t]; }
  __syncthreads();

  // O(K^2) stable rank sort (ties broken by original index)
  if (t < K) {
    float v = s_pos[t];
    int r = 0;
    for (int j = 0; j < K; ++j) {
      float u = s_pos[j];
      r += ((u < v) || (u == v && j < t)) ? 1 : 0;
    }
    s_x[r] = v;
  }
  __syncthreads();

  // contributions c[i] = (sx[i+1]-sx[i]) * slope[i]
  if (t < K - 1) s_c[t] = (s_x[t + 1] - s_x[t]) * s_slope[t];
  __syncthreads();
  // Hillis-Steele inclusive scan (7 rounds)
  for (int off = 1; off < K - 1; off <<= 1) {
    float v = 0.0f;
    if (t >= off && t < K - 1) v = s_c[t - off];
    __syncthreads();
    if (t < K - 1) s_c[t] += v;
    __syncthreads();
  }
  // beta[i] = bias + cum[i-1]; fold to y = a*x + (beta - sx*a)
  if (t < K) {
    float beta = bias[0] + (t ? s_c[t - 1] : 0.0f);
    float a = s_slope[t];
    s_sa[t] = a;
    s_sb[t] = beta - s_x[t] * a;
  }
  __syncthreads();

  if (t < K) {
    sx_g[t] = s_x[t];
    ab_g[t] = make_float2(s_sa[t], s_sb[t]);
  }

  // cnt[e] = #breakpoints <= e/NB, via binary upper_bound
  for (int e = t; e <= NB; e += blockDim.x) {
    float ev = (float)e * (1.0f / (float)NB);  // exact (pow2 scale)
    int lo = 0, hi = K;
    while (lo < hi) {
      int mid = (lo + hi) >> 1;
      if (s_x[mid] <= ev) lo = mid + 1; else hi = mid;
    }
    s_cnt[e] = (unsigned short)lo;
  }
  __syncthreads();

  // direct bucket table (AoS float2)
  for (int b = t; b < NB; b += blockDim.x) {
    int lo = s_cnt[b], hi = s_cnt[b + 1];
    float2 e;
    if (lo == hi) {                      // clean: segment fully determined
      int idx = min(max(lo, 1), K) - 1;  // clip(cnt,1,K)-1
      e = make_float2(s_sa[idx], s_sb[idx]);
    } else {                             // dirty: marker + packed search range
      e.x = __builtin_huge_valf();
      e.y = __uint_as_float((unsigned)lo | ((unsigned)hi << 16));
    }
    bab_g[b] = e;
  }
}

// ---------------------------------------------------------------------------
// Main streaming kernel.
// ---------------------------------------------------------------------------
__global__ __launch_bounds__(256, 8) void pwl_main_kernel(
    const fvec4* __restrict__ x, const float2* __restrict__ bab_g,
    const float* __restrict__ sx_g, const float2* __restrict__ ab_g,
    fvec4* __restrict__ out, int n4, int n) {
  __shared__ float2 s_bab[NB];
  __shared__ float s_x[K];
  __shared__ float2 s_ab[K];
  for (int i = threadIdx.x; i < NB; i += blockDim.x) s_bab[i] = bab_g[i];
  if (threadIdx.x < K) {
    s_x[threadIdx.x] = sx_g[threadIdx.x];
    s_ab[threadIdx.x] = ab_g[threadIdx.x];
  }
  __syncthreads();

  const int stride = gridDim.x * blockDim.x;
  int i0 = blockIdx.x * blockDim.x + threadIdx.x;
  int i1 = i0 + stride;
  bool h0 = i0 < n4;
  bool h1 = i1 < n4;
  fvec4 v0 = {}, v1 = {};
  if (h0) v0 = x[i0];
  if (h1) v1 = x[i1];

  while (h0) {
    int j0 = i0 + 2 * stride;
    int j1 = i1 + 2 * stride;
    bool g0 = j0 < n4;
    bool g1 = j1 < n4;
    fvec4 w0 = {}, w1 = {};
    if (g0) w0 = x[j0];
    if (g1) w1 = x[j1];

    // ---- 8 elements: batch all bucket computes, then all 8 ds_read_b64 ----
    float xe[8];
    xe[0] = v0.x; xe[1] = v0.y; xe[2] = v0.z; xe[3] = v0.w;
    xe[4] = v1.x; xe[5] = v1.y; xe[6] = v1.z; xe[7] = v1.w;

    float2 ab[8];
#pragma unroll
    for (int e = 0; e < 8; ++e) {
      int b = (int)(xe[e] * (float)NB);  // exact pow2 scale
      b = min(max(b, 0), NB - 1);
      ab[e] = s_bab[b];                  // independent b64 gathers, one drain
    }

    unsigned dirty = 0;
#pragma unroll
    for (int e = 0; e < 8; ++e)
      dirty |= (__float_as_uint(ab[e].x) == 0x7f800000u) ? (1u << e) : 0u;

    if (dirty) {  // rare-lane fixup, once per 8 elements
#pragma unroll
      for (int e = 0; e < 8; ++e) {
        if (dirty & (1u << e)) {
          unsigned p = __float_as_uint(ab[e].y);
          int lo = (int)(p & 0xffffu);
          int hi = (int)(p >> 16);
          while (lo < hi) {  // usually 1 iteration (hi-lo==1)
            int mid = (lo + hi) >> 1;
            if (s_x[mid] <= xe[e]) lo = mid + 1; else hi = mid;
          }
          int idx = min(max(lo, 1), K) - 1;
          ab[e] = s_ab[idx];
        }
      }
    }

    float y[8];
#pragma unroll
    for (int e = 0; e < 8; ++e)
      y[e] = fminf(fmaxf(fmaf(xe[e], ab[e].x, ab[e].y), 0.0f), 1.0f);

    fvec4 r0, r1;
    r0.x = y[0]; r0.y = y[1]; r0.z = y[2]; r0.w = y[3];
    r1.x = y[4]; r1.y = y[5]; r1.z = y[6]; r1.w = y[7];
    __builtin_nontemporal_store(r0, &out[i0]);
    if (h1) __builtin_nontemporal_store(r1, &out[i1]);

    i0 = j0; i1 = j1;
    v0 = w0; v1 = w1;
    h0 = g0; h1 = g1;
  }

  // scalar tail (n % 4), handled by block 0 (empty for this shape)
  if (blockIdx.x == 0) {
    const float* xs = (const float*)x;
    float* os = (float*)out;
    for (int j = (n4 << 2) + threadIdx.x; j < n; j += blockDim.x) {
      float xv = xs[j];
      int b = min(max((int)(xv * (float)NB), 0), NB - 1);
      float2 ab = s_bab[b];
      if (__float_as_uint(ab.x) == 0x7f800000u) {
        unsigned p = __float_as_uint(ab.y);
        int lo = (int)(p & 0xffffu);
        int hi = (int)(p >> 16);
        while (lo < hi) {
          int mid = (lo + hi) >> 1;
          if (s_x[mid] <= xv) lo = mid + 1; else hi = mid;
        }
        int idx = min(max(lo, 1), K) - 1;
        ab = s_ab[idx];
      }
      os[j] = fminf(fmaxf(fmaf(xv, ab.x, ab.y), 0.0f), 1.0f);
    }
  }
}

extern "C" void kernel_launch(void* const* d_in, const int* in_sizes, int n_in,
                              void* d_out, int out_size, void* d_ws, size_t ws_size,
                              hipStream_t stream) {
  const float* x    = (const float*)d_in[0];
  const float* xp   = (const float*)d_in[1];
  const float* sl   = (const float*)d_in[2];
  const float* bias = (const float*)d_in[3];
  float* out = (float*)d_out;

  float2* bab = (float2*)d_ws;                          // 8192 B
  float* sx   = (float*)((char*)d_ws + NB * 8);         // 400 B (+pad)
  float2* ab  = (float2*)((char*)d_ws + NB * 8 + 512);  // 800 B, 8B-aligned

  const int n  = in_sizes[0];
  const int n4 = n >> 2;

  pwl_setup_kernel<<<1, 1024, 0, stream>>>(xp, sl, bias, bab, sx, ab);

  const int threads = 256;
  const int blocks  = 2048;  // 8 blocks/CU * 4 waves = full 32 waves/CU
  pwl_main_kernel<<<blocks, threads, 0, stream>>>(
      (const fvec4*)x, bab, sx, ab, (fvec4*)out, n4, n);
}

// Round 7
// 241.223 us; speedup vs baseline: 1.0681x; 1.0414x over previous
//
#include <hip/hip_runtime.h>

#define K  100   // NUM_BREAKPOINTS
#define NB 1024  // LUT buckets (power of 2 -> exact fp bucket math)

typedef float fvec4 __attribute__((ext_vector_type(4)));

// ---------------------------------------------------------------------------
// rd0 measured-best structure (236.5 us e2e): two kernels, AoS float2 direct
// table (ONE ds_read_b64 per element), depth-1 software pipeline, 2048x256.
// Round-6 variable: PLAIN stores (all prior rounds used nontemporal stores;
// our kernel and rocclr copyBuffer both plateau at ~80us/2.5TB/s with nt
// stores while the fill kernel sinks 6.7TB/s with plain streaming stores).
// Loads stay plain (L3-resident x, FETCH 65MB of 134MB confirmed rd3).
//
// ws layout: [0,8192)      float2 bab[NB]
//            [8192,8592)   f32 sx[K]
//            [8704,9504)   float2 ab[K]
// ---------------------------------------------------------------------------
__global__ __launch_bounds__(1024) void pwl_setup_kernel(
    const float* __restrict__ xp, const float* __restrict__ sl,
    const float* __restrict__ bias, float2* __restrict__ bab_g,
    float* __restrict__ sx_g, float2* __restrict__ ab_g) {
  __shared__ float s_pos[K];
  __shared__ float s_slope[K];
  __shared__ float s_x[K];    // sorted breakpoints
  __shared__ float s_c[K];    // scan scratch
  __shared__ float s_sa[K];   // per-segment slope
  __shared__ float s_sb[K];   // per-segment intercept
  __shared__ unsigned short s_cnt[NB + 1];
  const int t = threadIdx.x;

  if (t < K) { s_pos[t] = xp[t]; s_slope[t] = sl[t]; }
  __syncthreads();

  // O(K^2) stable rank sort (ties broken by original index)
  if (t < K) {
    float v = s_pos[t];
    int r = 0;
    for (int j = 0; j < K; ++j) {
      float u = s_pos[j];
      r += ((u < v) || (u == v && j < t)) ? 1 : 0;
    }
    s_x[r] = v;
  }
  __syncthreads();

  // contributions c[i] = (sx[i+1]-sx[i]) * slope[i]
  if (t < K - 1) s_c[t] = (s_x[t + 1] - s_x[t]) * s_slope[t];
  __syncthreads();
  // Hillis-Steele inclusive scan (7 rounds)
  for (int off = 1; off < K - 1; off <<= 1) {
    float v = 0.0f;
    if (t >= off && t < K - 1) v = s_c[t - off];
    __syncthreads();
    if (t < K - 1) s_c[t] += v;
    __syncthreads();
  }
  // beta[i] = bias + cum[i-1]; fold to y = a*x + (beta - sx*a)
  if (t < K) {
    float beta = bias[0] + (t ? s_c[t - 1] : 0.0f);
    float a = s_slope[t];
    s_sa[t] = a;
    s_sb[t] = beta - s_x[t] * a;
  }
  __syncthreads();

  if (t < K) {
    sx_g[t] = s_x[t];
    ab_g[t] = make_float2(s_sa[t], s_sb[t]);
  }

  // cnt[e] = #breakpoints <= e/NB, via binary upper_bound
  for (int e = t; e <= NB; e += blockDim.x) {
    float ev = (float)e * (1.0f / (float)NB);  // exact (pow2 scale)
    int lo = 0, hi = K;
    while (lo < hi) {
      int mid = (lo + hi) >> 1;
      if (s_x[mid] <= ev) lo = mid + 1; else hi = mid;
    }
    s_cnt[e] = (unsigned short)lo;
  }
  __syncthreads();

  // direct bucket table (AoS float2)
  for (int b = t; b < NB; b += blockDim.x) {
    int lo = s_cnt[b], hi = s_cnt[b + 1];
    float2 e;
    if (lo == hi) {                      // clean: segment fully determined
      int idx = min(max(lo, 1), K) - 1;  // clip(cnt,1,K)-1
      e = make_float2(s_sa[idx], s_sb[idx]);
    } else {                             // dirty: marker + packed search range
      e.x = __builtin_huge_valf();
      e.y = __uint_as_float((unsigned)lo | ((unsigned)hi << 16));
    }
    bab_g[b] = e;
  }
}

// ---------------------------------------------------------------------------
// Main streaming kernel (rd0 structure, plain loads AND plain stores).
// ---------------------------------------------------------------------------
__device__ __forceinline__ float pwl_eval(float xv,
                                          const float2* __restrict__ s_bab,
                                          const float* __restrict__ s_x,
                                          const float2* __restrict__ s_ab) {
  int b = (int)(xv * (float)NB);  // exact pow2 scale; trunc toward 0
  b = min(max(b, 0), NB - 1);
  float2 ab = s_bab[b];
  if (__float_as_uint(ab.x) == 0x7f800000u) {  // dirty bucket (~9%)
    unsigned p = __float_as_uint(ab.y);
    int lo = (int)(p & 0xffffu);
    int hi = (int)(p >> 16);
    while (lo < hi) {  // upper_bound; dirty buckets usually have hi-lo==1
      int mid = (lo + hi) >> 1;
      if (s_x[mid] <= xv) lo = mid + 1; else hi = mid;
    }
    int idx = min(max(lo, 1), K) - 1;
    ab = s_ab[idx];
  }
  float y = fmaf(xv, ab.x, ab.y);
  return fminf(fmaxf(y, 0.0f), 1.0f);
}

__global__ __launch_bounds__(256) void pwl_main_kernel(
    const fvec4* __restrict__ x, const float2* __restrict__ bab_g,
    const float* __restrict__ sx_g, const float2* __restrict__ ab_g,
    fvec4* __restrict__ out, int n4, int n) {
  __shared__ float2 s_bab[NB];
  __shared__ float s_x[K];
  __shared__ float2 s_ab[K];
  for (int i = threadIdx.x; i < NB; i += blockDim.x) s_bab[i] = bab_g[i];
  if (threadIdx.x < K) {
    s_x[threadIdx.x] = sx_g[threadIdx.x];
    s_ab[threadIdx.x] = ab_g[threadIdx.x];
  }
  __syncthreads();

  const int stride = gridDim.x * blockDim.x;
  int i = blockIdx.x * blockDim.x + threadIdx.x;
  if (i < n4) {
    // software-pipelined: next load in flight while processing current
    fvec4 v = x[i];
    while (true) {
      int inext = i + stride;
      bool more = inext < n4;
      fvec4 vn = {};
      if (more) vn = x[inext];
      fvec4 r;
      r.x = pwl_eval(v.x, s_bab, s_x, s_ab);
      r.y = pwl_eval(v.y, s_bab, s_x, s_ab);
      r.z = pwl_eval(v.z, s_bab, s_x, s_ab);
      r.w = pwl_eval(v.w, s_bab, s_x, s_ab);
      out[i] = r;  // PLAIN store: through L2/L3, writeback drains post-kernel
      if (!more) break;
      v = vn;
      i = inext;
    }
  }

  // scalar tail (n % 4), handled by block 0 (empty for this shape)
  if (blockIdx.x == 0) {
    const float* xs = (const float*)x;
    float* os = (float*)out;
    for (int j = (n4 << 2) + threadIdx.x; j < n; j += blockDim.x) {
      os[j] = pwl_eval(xs[j], s_bab, s_x, s_ab);
    }
  }
}

extern "C" void kernel_launch(void* const* d_in, const int* in_sizes, int n_in,
                              void* d_out, int out_size, void* d_ws, size_t ws_size,
                              hipStream_t stream) {
  const float* x    = (const float*)d_in[0];
  const float* xp   = (const float*)d_in[1];
  const float* sl   = (const float*)d_in[2];
  const float* bias = (const float*)d_in[3];
  float* out = (float*)d_out;

  float2* bab = (float2*)d_ws;                          // 8192 B
  float* sx   = (float*)((char*)d_ws + NB * 8);         // 400 B (+pad)
  float2* ab  = (float2*)((char*)d_ws + NB * 8 + 512);  // 800 B, 8B-aligned

  const int n  = in_sizes[0];
  const int n4 = n >> 2;

  pwl_setup_kernel<<<1, 1024, 0, stream>>>(xp, sl, bias, bab, sx, ab);

  const int threads = 256;
  const int blocks  = 2048;  // 8 blocks/CU * 4 waves = full 32 waves/CU
  pwl_main_kernel<<<blocks, threads, 0, stream>>>(
      (const fvec4*)x, bab, sx, ab, (fvec4*)out, n4, n);
}